// Round 7
// baseline (1744.306 us; speedup 1.0000x reference)
//
#include <hip/hip_runtime.h>

#define NG 8192
#define LN_EPS 1e-5f

typedef float v2f __attribute__((ext_vector_type(2)));

// ---------------- DPP wave-scan helpers (VALU-only, no LDS pipe) ----------------

__device__ __forceinline__ float wscan_add(float x) {
  x += __int_as_float(__builtin_amdgcn_update_dpp(0, __float_as_int(x), 0x111, 0xF, 0xF, true));
  x += __int_as_float(__builtin_amdgcn_update_dpp(0, __float_as_int(x), 0x112, 0xF, 0xF, true));
  x += __int_as_float(__builtin_amdgcn_update_dpp(0, __float_as_int(x), 0x114, 0xF, 0xF, true));
  x += __int_as_float(__builtin_amdgcn_update_dpp(0, __float_as_int(x), 0x118, 0xF, 0xF, true));
  x += __int_as_float(__builtin_amdgcn_update_dpp(0, __float_as_int(x), 0x142, 0xA, 0xF, false));
  x += __int_as_float(__builtin_amdgcn_update_dpp(0, __float_as_int(x), 0x143, 0xC, 0xF, false));
  return x;
}

__device__ __forceinline__ int wscan_max(int x) {
  int t;
  t = __builtin_amdgcn_update_dpp(0, x, 0x111, 0xF, 0xF, true); x = max(x, t);
  t = __builtin_amdgcn_update_dpp(0, x, 0x112, 0xF, 0xF, true); x = max(x, t);
  t = __builtin_amdgcn_update_dpp(0, x, 0x114, 0xF, 0xF, true); x = max(x, t);
  t = __builtin_amdgcn_update_dpp(0, x, 0x118, 0xF, 0xF, true); x = max(x, t);
  t = __builtin_amdgcn_update_dpp(0, x, 0x142, 0xA, 0xF, false); x = max(x, t);
  t = __builtin_amdgcn_update_dpp(0, x, 0x143, 0xC, 0xF, false); x = max(x, t);
  return x;
}

__device__ __forceinline__ float wshr1(float x) {   // lane-1 value, 0 into lane0
  return __int_as_float(__builtin_amdgcn_update_dpp(0, __float_as_int(x), 0x138, 0xF, 0xF, false));
}

// ---------------- misc helpers ----------------

__device__ __forceinline__ void load20v(const float* __restrict__ p, v2f v[10]) {
  const float4* q = (const float4*)p;
#pragma unroll
  for (int t = 0; t < 5; t++) {
    float4 f = q[t];
    v[2*t]   = (v2f){f.x, f.y};
    v[2*t+1] = (v2f){f.z, f.w};
  }
}

__device__ __forceinline__ void store20v(float* __restrict__ p, const v2f v[10]) {
  float4* q = (float4*)p;
#pragma unroll
  for (int t = 0; t < 5; t++)
    q[t] = make_float4(v[2*t].x, v[2*t].y, v[2*t+1].x, v[2*t+1].y);
}

__device__ __forceinline__ float elem(const v2f* a, int k) { return a[k >> 1][k & 1]; }

// LN(relu(relu(h1)@W2+b2)@W3+b3)*g+be — single stream, SGPR weights.
__device__ __forceinline__ void mlp23_ln1(
    const float* __restrict__ W2, const float* __restrict__ b2,
    const float* __restrict__ W3, const float* __restrict__ b3,
    const float* __restrict__ g,  const float* __restrict__ be,
    const v2f h1[10], v2f out[10]) {
  const v2f* W2v = (const v2f*)W2; const v2f* b2v = (const v2f*)b2;
  const v2f* W3v = (const v2f*)W3; const v2f* b3v = (const v2f*)b3;
  const v2f* gv  = (const v2f*)g;  const v2f* bev = (const v2f*)be;
  v2f h2[10];
#pragma unroll
  for (int j = 0; j < 10; j++) h2[j] = b2v[j];
#pragma unroll
  for (int k = 0; k < 20; k++) {
    float a = fmaxf(elem(h1, k), 0.0f); v2f av = {a, a};
#pragma unroll
    for (int j = 0; j < 10; j++) h2[j] += av * W2v[k*10 + j];
  }
  v2f h3[10];
#pragma unroll
  for (int j = 0; j < 10; j++) h3[j] = b3v[j];
#pragma unroll
  for (int k = 0; k < 20; k++) {
    float a = fmaxf(elem(h2, k), 0.0f); v2f av = {a, a};
#pragma unroll
    for (int j = 0; j < 10; j++) h3[j] += av * W3v[k*10 + j];
  }
  float mu = 0.0f;
#pragma unroll
  for (int j = 0; j < 10; j++) mu += h3[j].x + h3[j].y;
  mu *= 0.05f;
  float var = 0.0f;
#pragma unroll
  for (int j = 0; j < 10; j++) {
    float dx = h3[j].x - mu, dy = h3[j].y - mu;
    var += dx*dx + dy*dy;
  }
  var *= 0.05f;
  float rs = rsqrtf(var + LN_EPS);
  v2f muv = {mu, mu}, rsv = {rs, rs};
#pragma unroll
  for (int j = 0; j < 10; j++) out[j] = (h3[j] - muv) * rsv * gv[j] + bev[j];
}

// Dual-node variant: one SGPR weight fetch feeds two independent FMA chains.
__device__ __forceinline__ void mlp23_ln2(
    const float* __restrict__ W2, const float* __restrict__ b2,
    const float* __restrict__ W3, const float* __restrict__ b3,
    const float* __restrict__ g,  const float* __restrict__ be,
    const v2f h1a[10], const v2f h1b[10], v2f outa[10], v2f outb[10]) {
  const v2f* W2v = (const v2f*)W2; const v2f* b2v = (const v2f*)b2;
  const v2f* W3v = (const v2f*)W3; const v2f* b3v = (const v2f*)b3;
  const v2f* gv  = (const v2f*)g;  const v2f* bev = (const v2f*)be;
  v2f h2a[10], h2b[10];
#pragma unroll
  for (int j = 0; j < 10; j++) { h2a[j] = b2v[j]; h2b[j] = b2v[j]; }
#pragma unroll
  for (int k = 0; k < 20; k++) {
    float aa = fmaxf(elem(h1a, k), 0.0f), ab = fmaxf(elem(h1b, k), 0.0f);
    v2f va = {aa, aa}, vb = {ab, ab};
#pragma unroll
    for (int j = 0; j < 10; j++) {
      v2f w = W2v[k*10 + j];
      h2a[j] += va * w; h2b[j] += vb * w;
    }
  }
  v2f h3a[10], h3b[10];
#pragma unroll
  for (int j = 0; j < 10; j++) { h3a[j] = b3v[j]; h3b[j] = b3v[j]; }
#pragma unroll
  for (int k = 0; k < 20; k++) {
    float aa = fmaxf(elem(h2a, k), 0.0f), ab = fmaxf(elem(h2b, k), 0.0f);
    v2f va = {aa, aa}, vb = {ab, ab};
#pragma unroll
    for (int j = 0; j < 10; j++) {
      v2f w = W3v[k*10 + j];
      h3a[j] += va * w; h3b[j] += vb * w;
    }
  }
  float mua = 0.0f, mub = 0.0f;
#pragma unroll
  for (int j = 0; j < 10; j++) {
    mua += h3a[j].x + h3a[j].y;
    mub += h3b[j].x + h3b[j].y;
  }
  mua *= 0.05f; mub *= 0.05f;
  float vara = 0.0f, varb = 0.0f;
#pragma unroll
  for (int j = 0; j < 10; j++) {
    float dx = h3a[j].x - mua, dy = h3a[j].y - mua; vara += dx*dx + dy*dy;
    float ex = h3b[j].x - mub, ey = h3b[j].y - mub; varb += ex*ex + ey*ey;
  }
  vara *= 0.05f; varb *= 0.05f;
  float rsa = rsqrtf(vara + LN_EPS), rsb = rsqrtf(varb + LN_EPS);
  v2f mva = {mua, mua}, rva = {rsa, rsa};
  v2f mvb = {mub, mub}, rvb = {rsb, rsb};
#pragma unroll
  for (int j = 0; j < 10; j++) {
    v2f gj = gv[j], bj = bev[j];
    outa[j] = (h3a[j] - mva) * rva * gj + bj;
    outb[j] = (h3b[j] - mvb) * rvb * gj + bj;
  }
}

// ---------------- kernels ----------------

__global__ __launch_bounds__(256) void k_prelayer(
    float* __restrict__ u, float* __restrict__ part, float* __restrict__ gu,
    const float* __restrict__ nmb1, const float* __restrict__ gpb1) {
  int t = blockIdx.x * 256 + threadIdx.x;   // NG*80 threads
  part[t] = 0.0f;
  if (t < NG * 40) {
    int j = t % 40;
    gu[t] = (j < 20) ? nmb1[j] : gpb1[j - 20];
  }
  if (t < NG * 20) u[t] = 0.0f;
}

__global__ __launch_bounds__(256) void k_init(
    const float* __restrict__ xin, float* __restrict__ xs,
    const float* __restrict__ W1, const float* __restrict__ b1,
    const float* __restrict__ W2, const float* __restrict__ b2,
    const float* __restrict__ W3, const float* __restrict__ b3,
    const float* __restrict__ gw, const float* __restrict__ bw, int n) {
  int i = blockIdx.x * 256 + threadIdx.x;
  if (i >= n) return;
  float xi[10];
  const float2* xp = (const float2*)(xin + (size_t)i * 10);
#pragma unroll
  for (int t = 0; t < 5; t++) { float2 f = xp[t]; xi[t*2] = f.x; xi[t*2+1] = f.y; }
  const v2f* W1v = (const v2f*)W1; const v2f* b1v = (const v2f*)b1;
  v2f h1[10];
#pragma unroll
  for (int j = 0; j < 10; j++) h1[j] = b1v[j];
#pragma unroll
  for (int k = 0; k < 10; k++) {
    float a = xi[k]; v2f av = {a, a};
#pragma unroll
    for (int j = 0; j < 10; j++) h1[j] += av * W1v[k*10 + j];
  }
  v2f out[10];
  mlp23_ln1(W2, b2, W3, b3, gw, bw, h1, out);
  store20v(xs + (size_t)i * 20, out);
}

// Per-layer node kernel, 2 NODES/THREAD: each wave covers 128 sorted nodes,
// so one SGPR weight stream serves 2x the work. Deterministic aggregation:
// pair-combine -> DPP unsegmented scan -> runsum = incl - incl[start-1];
// run-end lanes STORE to slot (i>>7)&3 of part[graph][4][20]; a mid-pair
// batch boundary ("orphan") stores pre0 + runsum@(lane-1). All cross-lane ops
// execute with full exec (outside divergence). No atomics -> replay-stable.
__global__ __launch_bounds__(256) void k_node(
    const int* __restrict__ batch, float* __restrict__ xs,
    const float* __restrict__ gu, float* __restrict__ part,
    const float* __restrict__ nmW1, const float* __restrict__ nmW2,
    const float* __restrict__ nmW3, const float* __restrict__ nmb2,
    const float* __restrict__ nmb3, const float* __restrict__ nmg,
    const float* __restrict__ nmbe,
    const float* __restrict__ gpW1, const float* __restrict__ gpW2,
    const float* __restrict__ gpW3, const float* __restrict__ gpb2,
    const float* __restrict__ gpb3, const float* __restrict__ gpg,
    const float* __restrict__ gpbe, int n) {
  int p = blockIdx.x * 256 + threadIdx.x;
  int lane = threadIdx.x & 63;
  int i0 = 2 * p, i1 = 2 * p + 1;
  bool v0 = i0 < n, v1 = i1 < n;
  int ic0 = v0 ? i0 : (n - 1);
  int ic1 = v1 ? i1 : (n - 1);
  int b0 = batch[ic0];
  int b1 = batch[ic1];

  v2f x0[10], x1[10];
  load20v(xs + (size_t)ic0 * 20, x0);
  load20v(xs + (size_t)ic1 * 20, x1);

  // ---- NodeModel: h1 = x@W1x + gu_nm[b]  (gu = u@W1u + b1, prefolded) ----
  v2f h1a[10], h1b[10];
  load20v(gu + (size_t)b0 * 40, h1a);
  load20v(gu + (size_t)b1 * 40, h1b);
  const v2f* W1v = (const v2f*)nmW1;
#pragma unroll
  for (int k = 0; k < 20; k++) {
    float aa = elem(x0, k), ab = elem(x1, k);
    v2f va = {aa, aa}, vb = {ab, ab};
#pragma unroll
    for (int j = 0; j < 10; j++) {
      v2f w = W1v[k*10 + j];
      h1a[j] += va * w; h1b[j] += vb * w;
    }
  }
  v2f xna[10], xnb[10];
  mlp23_ln2(nmW2, nmb2, nmW3, nmb3, nmg, nmbe, h1a, h1b, xna, xnb);
#pragma unroll
  for (int j = 0; j < 10; j++) { xna[j] += x0[j]; xnb[j] += x1[j]; }  // residual
  if (v0) store20v(xs + (size_t)ic0 * 20, xna);
  if (v1) store20v(xs + (size_t)ic1 * 20, xnb);

  // ---- pre-aggr MLP on updated x ----
  v2f p1a[10], p1b[10];
  load20v(gu + (size_t)b0 * 40 + 20, p1a);
  load20v(gu + (size_t)b1 * 40 + 20, p1b);
  const v2f* G1v = (const v2f*)gpW1;
#pragma unroll
  for (int k = 0; k < 20; k++) {
    float aa = elem(xna, k), ab = elem(xnb, k);
    v2f va = {aa, aa}, vb = {ab, ab};
#pragma unroll
    for (int j = 0; j < 10; j++) {
      v2f w = G1v[k*10 + j];
      p1a[j] += va * w; p1b[j] += vb * w;
    }
  }
  v2f pre0[10], pre1[10];
  mlp23_ln2(gpW2, gpb2, gpW3, gpb3, gpg, gpbe, p1a, p1b, pre0, pre1);

  // ---- deterministic pair-aware DPP aggregation (batch sorted) ----
  int key = v1 ? b1 : (v0 ? b0 : -1);     // batch of thread's LAST valid node
  int sb0 = v0 ? b0 : -1;                 // batch of thread's FIRST valid node
  bool orph = v0 && v1 && (b0 != b1);
  v2f val[10];
#pragma unroll
  for (int j = 0; j < 10; j++) {
    v2f s = (v2f){0.0f, 0.0f};
    if (v0 && v1) s = (b0 == b1) ? (pre0[j] + pre1[j]) : pre1[j];
    else if (v0)  s = pre0[j];
    val[j] = s;
  }
  int pkk = __builtin_amdgcn_update_dpp(-1, key, 0x138, 0xF, 0xF, false); // prev key
  int nsb = __builtin_amdgcn_update_dpp(-2, sb0, 0x130, 0xF, 0xF, false); // next sb0
  bool isstart = (key != pkk);
  int st = wscan_max(isstart ? lane : 0);         // start lane of my key-run

  v2f incl[10];
#pragma unroll
  for (int j = 0; j < 10; j++) {
    incl[j].x = wscan_add(val[j].x);
    incl[j].y = wscan_add(val[j].y);
  }
  int pl = (st > 0) ? (st - 1) : 0;
  float use = (st > 0) ? 1.0f : 0.0f;
  v2f runsum[10], rsp[10];
#pragma unroll
  for (int j = 0; j < 10; j++) {
    float bx = __shfl(incl[j].x, pl);
    float by = __shfl(incl[j].y, pl);
    runsum[j].x = incl[j].x - use * bx;
    runsum[j].y = incl[j].y - use * by;
  }
#pragma unroll
  for (int j = 0; j < 10; j++) {                  // runsum at lane-1 (full exec)
    rsp[j].x = wshr1(runsum[j].x);
    rsp[j].y = wshr1(runsum[j].y);
  }

  int slot = (i0 >> 7) & 3;                       // i0,i1 share a 128-node window
  bool usep = v0 && (pkk == sb0);                 // prev lane continues b0's run
  if (orph) {                                     // b0's run ends at i0
    float* pp = part + (size_t)b0 * 80 + slot * 20;
    v2f o[10];
#pragma unroll
    for (int j = 0; j < 10; j++)
      o[j] = usep ? (pre0[j] + rsp[j]) : pre0[j];
    store20v(pp, o);
  }
  bool runend = (key >= 0) && (nsb != key);       // lane63: nsb=-2 -> true
  if (runend) {
    float* pp = part + (size_t)key * 80 + slot * 20;
    store20v(pp, runsum);
  }
}

// Per-layer global kernel (16 blocks x 512 thr = 2 waves/SIMD for SMEM-drain
// overlap; SGPR weights): sum 4 partial slots in FIXED order, u update
// (+residual), re-zero slots, write gu tables for the NEXT layer.
__global__ __launch_bounds__(512) void k_global(
    float* __restrict__ u, float* __restrict__ part, float* __restrict__ gu,
    const float* __restrict__ qW1, const float* __restrict__ qb1,
    const float* __restrict__ qW2, const float* __restrict__ qb2,
    const float* __restrict__ qW3, const float* __restrict__ qb3,
    const float* __restrict__ qg,  const float* __restrict__ qbe,
    const float* __restrict__ nmW1u, const float* __restrict__ nmb1n,
    const float* __restrict__ gpW1u, const float* __restrict__ gpb1n,
    int has_next) {
  int g = blockIdx.x * 512 + threadIdx.x;    // exactly NG threads
  float* pg = part + (size_t)g * 80;
  v2f s0[10], s1[10], s2[10], s3[10];
  load20v(pg,      s0);
  load20v(pg + 20, s1);
  load20v(pg + 40, s2);
  load20v(pg + 60, s3);
  v2f a[10];
#pragma unroll
  for (int j = 0; j < 10; j++) a[j] = ((s0[j] + s1[j]) + s2[j]) + s3[j];

  v2f uu[10];
  load20v(u + (size_t)g * 20, uu);
  const v2f* qW1v = (const v2f*)qW1; const v2f* qb1v = (const v2f*)qb1;
  v2f h1[10];
#pragma unroll
  for (int j = 0; j < 10; j++) h1[j] = qb1v[j];
#pragma unroll
  for (int k = 0; k < 20; k++) {
    float v = elem(a, k); v2f av = {v, v};
#pragma unroll
    for (int j = 0; j < 10; j++) h1[j] += av * qW1v[k*10 + j];
  }
#pragma unroll
  for (int k = 0; k < 20; k++) {
    float v = elem(uu, k); v2f av = {v, v};
#pragma unroll
    for (int j = 0; j < 10; j++) h1[j] += av * qW1v[200 + k*10 + j];
  }
  v2f un[10];
  mlp23_ln1(qW2, qb2, qW3, qb3, qg, qbe, h1, un);
#pragma unroll
  for (int j = 0; j < 10; j++) un[j] += uu[j];    // residual
  store20v(u + (size_t)g * 20, un);

  v2f z[10];
#pragma unroll
  for (int j = 0; j < 10; j++) z[j] = (v2f){0.0f, 0.0f};
  store20v(pg,      z);                            // re-zero slots for next layer
  store20v(pg + 20, z);
  store20v(pg + 40, z);
  store20v(pg + 60, z);

  if (has_next) {
    const v2f* nW = (const v2f*)nmW1u; const v2f* nb = (const v2f*)nmb1n;
    const v2f* gW = (const v2f*)gpW1u; const v2f* gb = (const v2f*)gpb1n;
    v2f gn[10], gg2[10];
#pragma unroll
    for (int j = 0; j < 10; j++) { gn[j] = nb[j]; gg2[j] = gb[j]; }
#pragma unroll
    for (int k = 0; k < 20; k++) {
      float v = elem(un, k); v2f av = {v, v};
#pragma unroll
      for (int j = 0; j < 10; j++) {
        gn[j]  += av * nW[k*10 + j];
        gg2[j] += av * gW[k*10 + j];
      }
    }
    store20v(gu + (size_t)g * 40, gn);
    store20v(gu + (size_t)g * 40 + 20, gg2);
  }
}

// ---------------- host launcher ----------------

extern "C" void kernel_launch(void* const* d_in, const int* in_sizes, int n_in,
                              void* d_out, int out_size, void* d_ws, size_t ws_size,
                              hipStream_t stream) {
  const float* x_in  = (const float*)d_in[0];
  const int*   batch = (const int*)  d_in[1];
  const float* ni_W1 = (const float*)d_in[2];
  const float* ni_b1 = (const float*)d_in[3];
  const float* ni_W2 = (const float*)d_in[4];
  const float* ni_b2 = (const float*)d_in[5];
  const float* ni_W3 = (const float*)d_in[6];
  const float* ni_b3 = (const float*)d_in[7];
  const float* ni_g  = (const float*)d_in[8];
  const float* ni_be = (const float*)d_in[9];
  const float* nm_W1 = (const float*)d_in[10];
  const float* nm_b1 = (const float*)d_in[11];
  const float* nm_W2 = (const float*)d_in[12];
  const float* nm_b2 = (const float*)d_in[13];
  const float* nm_W3 = (const float*)d_in[14];
  const float* nm_b3 = (const float*)d_in[15];
  const float* nm_g  = (const float*)d_in[16];
  const float* nm_be = (const float*)d_in[17];
  const float* gp_W1 = (const float*)d_in[18];
  const float* gp_b1 = (const float*)d_in[19];
  const float* gp_W2 = (const float*)d_in[20];
  const float* gp_b2 = (const float*)d_in[21];
  const float* gp_W3 = (const float*)d_in[22];
  const float* gp_b3 = (const float*)d_in[23];
  const float* gp_g  = (const float*)d_in[24];
  const float* gp_be = (const float*)d_in[25];
  const float* gq_W1 = (const float*)d_in[26];
  const float* gq_b1 = (const float*)d_in[27];
  const float* gq_W2 = (const float*)d_in[28];
  const float* gq_b2 = (const float*)d_in[29];
  const float* gq_W3 = (const float*)d_in[30];
  const float* gq_b3 = (const float*)d_in[31];
  const float* gq_g  = (const float*)d_in[32];
  const float* gq_be = (const float*)d_in[33];

  const int N = in_sizes[0] / 10;          // 500000
  float* xs = (float*)d_out;               // x state in d_out[0 .. N*20)
  float* u  = xs + (size_t)N * 20;         // u in d_out tail (NG*20)

  float* part = (float*)d_ws;              // NG*80 (4 slots x 20 per graph)
  float* gu   = part + NG * 80;            // NG*40 (merged nm|gp table)

  const int L = 20;
  const int nblk  = (N + 255) / 256;
  const int npair = (N + 1) / 2;
  const int nblkp = (npair + 255) / 256;

  k_prelayer<<<(NG * 80) / 256, 256, 0, stream>>>(u, part, gu, nm_b1, gp_b1);
  k_init<<<nblk, 256, 0, stream>>>(x_in, xs, ni_W1, ni_b1, ni_W2, ni_b2,
                                   ni_W3, ni_b3, ni_g, ni_be, N);
  for (int l = 0; l < L; l++) {
    k_node<<<nblkp, 256, 0, stream>>>(batch, xs, gu, part,
        nm_W1 + (size_t)l * 800, nm_W2 + (size_t)l * 400, nm_W3 + (size_t)l * 400,
        nm_b2 + l * 20, nm_b3 + l * 20, nm_g + l * 20, nm_be + l * 20,
        gp_W1 + (size_t)l * 800, gp_W2 + (size_t)l * 400, gp_W3 + (size_t)l * 400,
        gp_b2 + l * 20, gp_b3 + l * 20, gp_g + l * 20, gp_be + l * 20, N);
    int has_next = (l < L - 1);
    k_global<<<NG / 512, 512, 0, stream>>>(u, part, gu,
        gq_W1 + (size_t)l * 800, gq_b1 + l * 20,
        gq_W2 + (size_t)l * 400, gq_b2 + l * 20,
        gq_W3 + (size_t)l * 400, gq_b3 + l * 20,
        gq_g + l * 20, gq_be + l * 20,
        nm_W1 + (size_t)(l + 1) * 800 + 400, nm_b1 + (l + 1) * 20,
        gp_W1 + (size_t)(l + 1) * 800 + 400, gp_b1 + (l + 1) * 20,
        has_next);
  }
}

// Round 8
// 1499.087 us; speedup vs baseline: 1.1636x; 1.1636x over previous
//
#include <hip/hip_runtime.h>

#define NG 8192
#define LN_EPS 1e-5f

typedef float v2f __attribute__((ext_vector_type(2)));

// ---------------- DPP wave-scan helpers (VALU-only, no LDS pipe) ----------------

__device__ __forceinline__ float wscan_add(float x) {
  x += __int_as_float(__builtin_amdgcn_update_dpp(0, __float_as_int(x), 0x111, 0xF, 0xF, true));
  x += __int_as_float(__builtin_amdgcn_update_dpp(0, __float_as_int(x), 0x112, 0xF, 0xF, true));
  x += __int_as_float(__builtin_amdgcn_update_dpp(0, __float_as_int(x), 0x114, 0xF, 0xF, true));
  x += __int_as_float(__builtin_amdgcn_update_dpp(0, __float_as_int(x), 0x118, 0xF, 0xF, true));
  x += __int_as_float(__builtin_amdgcn_update_dpp(0, __float_as_int(x), 0x142, 0xA, 0xF, false));
  x += __int_as_float(__builtin_amdgcn_update_dpp(0, __float_as_int(x), 0x143, 0xC, 0xF, false));
  return x;
}

__device__ __forceinline__ int wscan_max(int x) {
  int t;
  t = __builtin_amdgcn_update_dpp(0, x, 0x111, 0xF, 0xF, true); x = max(x, t);
  t = __builtin_amdgcn_update_dpp(0, x, 0x112, 0xF, 0xF, true); x = max(x, t);
  t = __builtin_amdgcn_update_dpp(0, x, 0x114, 0xF, 0xF, true); x = max(x, t);
  t = __builtin_amdgcn_update_dpp(0, x, 0x118, 0xF, 0xF, true); x = max(x, t);
  t = __builtin_amdgcn_update_dpp(0, x, 0x142, 0xA, 0xF, false); x = max(x, t);
  t = __builtin_amdgcn_update_dpp(0, x, 0x143, 0xC, 0xF, false); x = max(x, t);
  return x;
}

// ---------------- misc helpers ----------------

__device__ __forceinline__ void stage4(float* dst, const float* __restrict__ src,
                                       int n4, int tid, int nt) {
  float4* d = (float4*)dst;
  const float4* s = (const float4*)src;
  for (int t = tid; t < n4; t += nt) d[t] = s[t];
}

__device__ __forceinline__ void load20v(const float* __restrict__ p, v2f v[10]) {
  const float4* q = (const float4*)p;
#pragma unroll
  for (int t = 0; t < 5; t++) {
    float4 f = q[t];
    v[2*t]   = (v2f){f.x, f.y};
    v[2*t+1] = (v2f){f.z, f.w};
  }
}

__device__ __forceinline__ void store20v(float* __restrict__ p, const v2f v[10]) {
  float4* q = (float4*)p;
#pragma unroll
  for (int t = 0; t < 5; t++)
    q[t] = make_float4(v[2*t].x, v[2*t].y, v[2*t+1].x, v[2*t+1].y);
}

__device__ __forceinline__ float elem(const v2f* a, int k) { return a[k >> 1][k & 1]; }

// LN(relu(relu(h1)@W2+b2)@W3+b3)*g+be — packed fp32 pairs. Works for both
// global (SGPR s_load) and LDS (broadcast ds_read) weight pointers (inlined).
__device__ __forceinline__ void mlp23_ln1(
    const float* __restrict__ W2, const float* __restrict__ b2,
    const float* __restrict__ W3, const float* __restrict__ b3,
    const float* __restrict__ g,  const float* __restrict__ be,
    const v2f h1[10], v2f out[10]) {
  const v2f* W2v = (const v2f*)W2; const v2f* b2v = (const v2f*)b2;
  const v2f* W3v = (const v2f*)W3; const v2f* b3v = (const v2f*)b3;
  const v2f* gv  = (const v2f*)g;  const v2f* bev = (const v2f*)be;
  v2f h2[10];
#pragma unroll
  for (int j = 0; j < 10; j++) h2[j] = b2v[j];
#pragma unroll
  for (int k = 0; k < 20; k++) {
    float a = fmaxf(elem(h1, k), 0.0f); v2f av = {a, a};
#pragma unroll
    for (int j = 0; j < 10; j++) h2[j] += av * W2v[k*10 + j];
  }
  v2f h3[10];
#pragma unroll
  for (int j = 0; j < 10; j++) h3[j] = b3v[j];
#pragma unroll
  for (int k = 0; k < 20; k++) {
    float a = fmaxf(elem(h2, k), 0.0f); v2f av = {a, a};
#pragma unroll
    for (int j = 0; j < 10; j++) h3[j] += av * W3v[k*10 + j];
  }
  float mu = 0.0f;
#pragma unroll
  for (int j = 0; j < 10; j++) mu += h3[j].x + h3[j].y;
  mu *= 0.05f;
  float var = 0.0f;
#pragma unroll
  for (int j = 0; j < 10; j++) {
    float dx = h3[j].x - mu, dy = h3[j].y - mu;
    var += dx*dx + dy*dy;
  }
  var *= 0.05f;
  float rs = rsqrtf(var + LN_EPS);
  v2f muv = {mu, mu}, rsv = {rs, rs};
#pragma unroll
  for (int j = 0; j < 10; j++) out[j] = (h3[j] - muv) * rsv * gv[j] + bev[j];
}

// ---------------- kernels ----------------

__global__ __launch_bounds__(256) void k_prelayer(
    float* __restrict__ u, float* __restrict__ part, float* __restrict__ gu,
    const float* __restrict__ nmb1, const float* __restrict__ gpb1) {
  int t = blockIdx.x * 256 + threadIdx.x;   // NG*80 threads
  part[t] = 0.0f;
  if (t < NG * 40) {
    int j = t % 40;
    gu[t] = (j < 20) ? nmb1[j] : gpb1[j - 20];
  }
  if (t < NG * 20) u[t] = 0.0f;
}

__global__ __launch_bounds__(256) void k_init(
    const float* __restrict__ xin, float* __restrict__ xs,
    const float* __restrict__ W1, const float* __restrict__ b1,
    const float* __restrict__ W2, const float* __restrict__ b2,
    const float* __restrict__ W3, const float* __restrict__ b3,
    const float* __restrict__ gw, const float* __restrict__ bw, int n) {
  int i = blockIdx.x * 256 + threadIdx.x;
  if (i >= n) return;
  float xi[10];
  const float2* xp = (const float2*)(xin + (size_t)i * 10);
#pragma unroll
  for (int t = 0; t < 5; t++) { float2 f = xp[t]; xi[t*2] = f.x; xi[t*2+1] = f.y; }
  const v2f* W1v = (const v2f*)W1; const v2f* b1v = (const v2f*)b1;
  v2f h1[10];
#pragma unroll
  for (int j = 0; j < 10; j++) h1[j] = b1v[j];
#pragma unroll
  for (int k = 0; k < 10; k++) {
    float a = xi[k]; v2f av = {a, a};
#pragma unroll
    for (int j = 0; j < 10; j++) h1[j] += av * W1v[k*10 + j];
  }
  v2f out[10];
  mlp23_ln1(W2, b2, W3, b3, gw, bw, h1, out);
  store20v(xs + (size_t)i * 20, out);
}

// Per-layer node kernel, 1 node/thread, pk-fp32. Weight traffic is SPLIT
// across both uniform-operand pipes: NodeModel MLP weights stream through
// the scalar path (s_load -> SGPR operands), pre-aggr MLP weights are staged
// once per block into LDS and read as broadcast ds_read_b128 (conflict-free).
// This halves the per-wave SMEM drain chain and uses the otherwise-idle LDS
// pipe. Aggregation: deterministic DPP scan + run-end slot STORES (no
// atomics -> bitwise replay-stable).
__global__ __launch_bounds__(256) void k_node(
    const int* __restrict__ batch, float* __restrict__ xs,
    const float* __restrict__ gu, float* __restrict__ part,
    const float* __restrict__ nmW1, const float* __restrict__ nmW2,
    const float* __restrict__ nmW3, const float* __restrict__ nmb2,
    const float* __restrict__ nmb3, const float* __restrict__ nmg,
    const float* __restrict__ nmbe,
    const float* __restrict__ gpW1, const float* __restrict__ gpW2,
    const float* __restrict__ gpW3, const float* __restrict__ gpb2,
    const float* __restrict__ gpb3, const float* __restrict__ gpg,
    const float* __restrict__ gpbe, int n) {
  __shared__ float sm[1280];
  int tid = threadIdx.x;
  stage4(sm + 0,    gpW1, 100, tid, 256);
  stage4(sm + 400,  gpW2, 100, tid, 256);
  stage4(sm + 800,  gpW3, 100, tid, 256);
  stage4(sm + 1200, gpb2, 5,   tid, 256);
  stage4(sm + 1220, gpb3, 5,   tid, 256);
  stage4(sm + 1240, gpg,  5,   tid, 256);
  stage4(sm + 1260, gpbe, 5,   tid, 256);
  __syncthreads();

  int i = blockIdx.x * 256 + tid;
  int lane = tid & 63;
  bool valid = i < n;
  int ic = valid ? i : (n - 1);
  int b = batch[ic];

  v2f x[10];
  load20v(xs + (size_t)ic * 20, x);

  // ---- NodeModel: h1 = x@W1x + gu_nm[b]  (gu = u@W1u + b1, prefolded) ----
  v2f h1[10];
  load20v(gu + (size_t)b * 40, h1);
  const v2f* W1v = (const v2f*)nmW1;
#pragma unroll
  for (int k = 0; k < 20; k++) {
    float a = elem(x, k); v2f av = {a, a};
#pragma unroll
    for (int j = 0; j < 10; j++) h1[j] += av * W1v[k*10 + j];
  }
  v2f xn[10];
  mlp23_ln1(nmW2, nmb2, nmW3, nmb3, nmg, nmbe, h1, xn);
#pragma unroll
  for (int j = 0; j < 10; j++) xn[j] += x[j];     // residual
  if (valid) store20v(xs + (size_t)ic * 20, xn);

  // ---- pre-aggr MLP on updated x (weights from LDS broadcast) ----
  v2f p1[10];
  load20v(gu + (size_t)b * 40 + 20, p1);
  const v2f* G1v = (const v2f*)sm;
#pragma unroll
  for (int k = 0; k < 20; k++) {
    float a = elem(xn, k); v2f av = {a, a};
#pragma unroll
    for (int j = 0; j < 10; j++) p1[j] += av * G1v[k*10 + j];
  }
  v2f pre[10];
  mlp23_ln1(sm + 400, sm + 1200, sm + 800, sm + 1220, sm + 1240, sm + 1260,
            p1, pre);

  // ---- aggregation: DPP scan + run-end slot stores (batch sorted) ----
  int key = valid ? b : -1;
  if (!valid) {
#pragma unroll
    for (int j = 0; j < 10; j++) pre[j] = (v2f){0.0f, 0.0f};
  }
  int pk = __builtin_amdgcn_update_dpp(-1, key, 0x138, 0xF, 0xF, false);
  int nk = __builtin_amdgcn_update_dpp(-2, key, 0x130, 0xF, 0xF, false);
  bool isstart = (key != pk);
  int st = wscan_max(isstart ? lane : 0);   // start lane of my run

#pragma unroll
  for (int j = 0; j < 10; j++) {
    pre[j].x = wscan_add(pre[j].x);
    pre[j].y = wscan_add(pre[j].y);
  }

  int pl = (st > 0) ? (st - 1) : 0;
  float use = (st > 0) ? 1.0f : 0.0f;
  v2f fl[10];
#pragma unroll
  for (int j = 0; j < 10; j++) {
    float bx = __shfl(pre[j].x, pl);
    float by = __shfl(pre[j].y, pl);
    fl[j].x = pre[j].x - use * bx;
    fl[j].y = pre[j].y - use * by;
  }
  bool runend = valid && (nk != key);       // lane63 gets nk=-2 -> true
  if (runend) {
    int slot = (i >> 6) & 3;                // graphs span <=4 consecutive waves
    float* pp = part + (size_t)b * 80 + slot * 20;
#pragma unroll
    for (int j = 0; j < 10; j++) {
      pp[2*j]     = fl[j].x;
      pp[2*j + 1] = fl[j].y;
    }
  }
}

// Per-layer global kernel (128 blocks x 64 thr, SGPR weights): sum the 4
// partial slots in FIXED order (deterministic), u update (+residual), re-zero
// slots for the next layer, write gu tables for the NEXT layer.
__global__ __launch_bounds__(64) void k_global(
    float* __restrict__ u, float* __restrict__ part, float* __restrict__ gu,
    const float* __restrict__ qW1, const float* __restrict__ qb1,
    const float* __restrict__ qW2, const float* __restrict__ qb2,
    const float* __restrict__ qW3, const float* __restrict__ qb3,
    const float* __restrict__ qg,  const float* __restrict__ qbe,
    const float* __restrict__ nmW1u, const float* __restrict__ nmb1n,
    const float* __restrict__ gpW1u, const float* __restrict__ gpb1n,
    int has_next) {
  int g = blockIdx.x * 64 + threadIdx.x;    // exactly NG threads
  float* pg = part + (size_t)g * 80;
  v2f s0[10], s1[10], s2[10], s3[10];
  load20v(pg,      s0);
  load20v(pg + 20, s1);
  load20v(pg + 40, s2);
  load20v(pg + 60, s3);
  v2f a[10];
#pragma unroll
  for (int j = 0; j < 10; j++) a[j] = ((s0[j] + s1[j]) + s2[j]) + s3[j];

  v2f uu[10];
  load20v(u + (size_t)g * 20, uu);
  const v2f* qW1v = (const v2f*)qW1; const v2f* qb1v = (const v2f*)qb1;
  v2f h1[10];
#pragma unroll
  for (int j = 0; j < 10; j++) h1[j] = qb1v[j];
#pragma unroll
  for (int k = 0; k < 20; k++) {
    float v = elem(a, k); v2f av = {v, v};
#pragma unroll
    for (int j = 0; j < 10; j++) h1[j] += av * qW1v[k*10 + j];
  }
#pragma unroll
  for (int k = 0; k < 20; k++) {
    float v = elem(uu, k); v2f av = {v, v};
#pragma unroll
    for (int j = 0; j < 10; j++) h1[j] += av * qW1v[200 + k*10 + j];
  }
  v2f un[10];
  mlp23_ln1(qW2, qb2, qW3, qb3, qg, qbe, h1, un);
#pragma unroll
  for (int j = 0; j < 10; j++) un[j] += uu[j];    // residual
  store20v(u + (size_t)g * 20, un);

  v2f z[10];
#pragma unroll
  for (int j = 0; j < 10; j++) z[j] = (v2f){0.0f, 0.0f};
  store20v(pg,      z);                            // re-zero slots for next layer
  store20v(pg + 20, z);
  store20v(pg + 40, z);
  store20v(pg + 60, z);

  if (has_next) {
    const v2f* nW = (const v2f*)nmW1u; const v2f* nb = (const v2f*)nmb1n;
    const v2f* gW = (const v2f*)gpW1u; const v2f* gb = (const v2f*)gpb1n;
    v2f gn[10], gg2[10];
#pragma unroll
    for (int j = 0; j < 10; j++) { gn[j] = nb[j]; gg2[j] = gb[j]; }
#pragma unroll
    for (int k = 0; k < 20; k++) {
      float v = elem(un, k); v2f av = {v, v};
#pragma unroll
      for (int j = 0; j < 10; j++) {
        gn[j]  += av * nW[k*10 + j];
        gg2[j] += av * gW[k*10 + j];
      }
    }
    store20v(gu + (size_t)g * 40, gn);
    store20v(gu + (size_t)g * 40 + 20, gg2);
  }
}

// ---------------- host launcher ----------------

extern "C" void kernel_launch(void* const* d_in, const int* in_sizes, int n_in,
                              void* d_out, int out_size, void* d_ws, size_t ws_size,
                              hipStream_t stream) {
  const float* x_in  = (const float*)d_in[0];
  const int*   batch = (const int*)  d_in[1];
  const float* ni_W1 = (const float*)d_in[2];
  const float* ni_b1 = (const float*)d_in[3];
  const float* ni_W2 = (const float*)d_in[4];
  const float* ni_b2 = (const float*)d_in[5];
  const float* ni_W3 = (const float*)d_in[6];
  const float* ni_b3 = (const float*)d_in[7];
  const float* ni_g  = (const float*)d_in[8];
  const float* ni_be = (const float*)d_in[9];
  const float* nm_W1 = (const float*)d_in[10];
  const float* nm_b1 = (const float*)d_in[11];
  const float* nm_W2 = (const float*)d_in[12];
  const float* nm_b2 = (const float*)d_in[13];
  const float* nm_W3 = (const float*)d_in[14];
  const float* nm_b3 = (const float*)d_in[15];
  const float* nm_g  = (const float*)d_in[16];
  const float* nm_be = (const float*)d_in[17];
  const float* gp_W1 = (const float*)d_in[18];
  const float* gp_b1 = (const float*)d_in[19];
  const float* gp_W2 = (const float*)d_in[20];
  const float* gp_b2 = (const float*)d_in[21];
  const float* gp_W3 = (const float*)d_in[22];
  const float* gp_b3 = (const float*)d_in[23];
  const float* gp_g  = (const float*)d_in[24];
  const float* gp_be = (const float*)d_in[25];
  const float* gq_W1 = (const float*)d_in[26];
  const float* gq_b1 = (const float*)d_in[27];
  const float* gq_W2 = (const float*)d_in[28];
  const float* gq_b2 = (const float*)d_in[29];
  const float* gq_W3 = (const float*)d_in[30];
  const float* gq_b3 = (const float*)d_in[31];
  const float* gq_g  = (const float*)d_in[32];
  const float* gq_be = (const float*)d_in[33];

  const int N = in_sizes[0] / 10;          // 500000
  float* xs = (float*)d_out;               // x state in d_out[0 .. N*20)
  float* u  = xs + (size_t)N * 20;         // u in d_out tail (NG*20)

  float* part = (float*)d_ws;              // NG*80 (4 slots x 20 per graph)
  float* gu   = part + NG * 80;            // NG*40 (merged nm|gp table)

  const int L = 20;
  const int nblk = (N + 255) / 256;

  k_prelayer<<<(NG * 80) / 256, 256, 0, stream>>>(u, part, gu, nm_b1, gp_b1);
  k_init<<<nblk, 256, 0, stream>>>(x_in, xs, ni_W1, ni_b1, ni_W2, ni_b2,
                                   ni_W3, ni_b3, ni_g, ni_be, N);
  for (int l = 0; l < L; l++) {
    k_node<<<nblk, 256, 0, stream>>>(batch, xs, gu, part,
        nm_W1 + (size_t)l * 800, nm_W2 + (size_t)l * 400, nm_W3 + (size_t)l * 400,
        nm_b2 + l * 20, nm_b3 + l * 20, nm_g + l * 20, nm_be + l * 20,
        gp_W1 + (size_t)l * 800, gp_W2 + (size_t)l * 400, gp_W3 + (size_t)l * 400,
        gp_b2 + l * 20, gp_b3 + l * 20, gp_g + l * 20, gp_be + l * 20, N);
    int has_next = (l < L - 1);
    k_global<<<NG / 64, 64, 0, stream>>>(u, part, gu,
        gq_W1 + (size_t)l * 800, gq_b1 + l * 20,
        gq_W2 + (size_t)l * 400, gq_b2 + l * 20,
        gq_W3 + (size_t)l * 400, gq_b3 + l * 20,
        gq_g + l * 20, gq_be + l * 20,
        nm_W1 + (size_t)(l + 1) * 800 + 400, nm_b1 + (l + 1) * 20,
        gp_W1 + (size_t)(l + 1) * 800 + 400, gp_b1 + (l + 1) * 20,
        has_next);
  }
}